// Round 1
// baseline (64.664 us; speedup 1.0000x reference)
//
#include <hip/hip_runtime.h>

// Problem constants
constexpr int cN1 = 85,  cF1 = 256, cO1 = 200, cE1 = 1360;
constexpr int cN2 = 5625, cF2 = 128, cE2 = 180000;

// Workspace layout (in 4-byte units). First ZERO_WORDS words are zeroed each call.
constexpr int OFF_G1   = 0;          // 17000 f32  (aggregated graph1 output, 85*200)
constexpr int OFF_G2   = 17000;      // 11250 f32  (aggregated graph2 output, 5625*2)
constexpr int OFF_DEG1 = 28250;      // 85    i32  (edge-dst counts, excl. self loop)
constexpr int OFF_DEG2 = 28335;      // 5625  i32
constexpr int ZERO_WORDS = 33960;
constexpr int OFF_H1   = 33960;      // 17000 f32  (x1 @ W1)
constexpr int OFF_H2   = 50960;      // 11250 f32  (x2 @ W2)  (even offset -> float2 ok)

// ---------------- K1: GEMMs + degree histogram (independent work) ----------------
// grid roles: [0,85) GEMM1 rows | [85,789) GEMM2 (8 rows/block) | [789,1498) degrees
constexpr int K1_GEMM2_BLOCKS = (cN2 + 7) / 8;                      // 704
constexpr int K1_DEG_BLOCKS   = (cE1 + cE2 + 255) / 256;            // 709
constexpr int K1_GRID = cN1 + K1_GEMM2_BLOCKS + K1_DEG_BLOCKS;      // 1498

__global__ __launch_bounds__(256) void k1_gemm_deg(
    const float* __restrict__ x1, const float* __restrict__ x2,
    const float* __restrict__ W1, const float* __restrict__ W2,
    const int* __restrict__ ei1, const int* __restrict__ ei2,
    float* __restrict__ ws_f, int* __restrict__ ws_i)
{
    int b = blockIdx.x, t = threadIdx.x;

    if (b < cN1) {
        // GEMM1: h1[b][t] = sum_k x1[b][k] * W1[k][t]   (t < 200)
        if (t < cO1) {
            const float* xr = x1 + b * cF1;          // uniform across block -> s-loads
            float s = 0.f;
            #pragma unroll 4
            for (int k = 0; k < cF1; ++k)
                s = fmaf(xr[k], W1[k * cO1 + t], s); // coalesced across t
            ws_f[OFF_H1 + b * cO1 + t] = s;
        }
        return;
    }
    b -= cN1;

    if (b < K1_GEMM2_BLOCKS) {
        // GEMM2: half-wave (32 lanes) per row; row has 128 f32 = 32 float4.
        __shared__ float sW2[cF2 * 2];
        sW2[t] = W2[t];                 // t in [0,256) == 128*2
        __syncthreads();
        int row = b * 8 + (t >> 5);
        int l   = t & 31;
        if (row < cN2) {
            float4 xv = reinterpret_cast<const float4*>(x2 + row * cF2)[l];
            int kb = l * 4;
            float p0 = xv.x * sW2[(kb + 0) * 2 + 0] + xv.y * sW2[(kb + 1) * 2 + 0]
                     + xv.z * sW2[(kb + 2) * 2 + 0] + xv.w * sW2[(kb + 3) * 2 + 0];
            float p1 = xv.x * sW2[(kb + 0) * 2 + 1] + xv.y * sW2[(kb + 1) * 2 + 1]
                     + xv.z * sW2[(kb + 2) * 2 + 1] + xv.w * sW2[(kb + 3) * 2 + 1];
            #pragma unroll
            for (int m = 16; m >= 1; m >>= 1) {      // reduce within 32-lane group
                p0 += __shfl_xor(p0, m);
                p1 += __shfl_xor(p1, m);
            }
            if (l == 0) {
                ws_f[OFF_H2 + row * 2 + 0] = p0;
                ws_f[OFF_H2 + row * 2 + 1] = p1;
            }
        }
        return;
    }
    b -= K1_GEMM2_BLOCKS;

    // Degree histogram over dst of all real edges (self-loop handled as +1 later)
    int idx = b * 256 + t;
    if (idx < cE1) {
        atomicAdd(&ws_i[OFF_DEG1 + ei1[cE1 + idx]], 1);
    } else {
        idx -= cE1;
        if (idx < cE2) atomicAdd(&ws_i[OFF_DEG2 + ei2[cE2 + idx]], 1);
    }
}

// ---------------- K2: normalized scatter-add (incl. self loops) ----------------
// grid roles: [0, 1445) one block per graph1 edge | rest: 256 graph2 edges/block
constexpr int K2_G1_BLOCKS = cE1 + cN1;                              // 1445
constexpr int K2_G2_BLOCKS = (cE2 + cN2 + 255) / 256;                // 726
constexpr int K2_GRID = K2_G1_BLOCKS + K2_G2_BLOCKS;                 // 2171

__global__ __launch_bounds__(256) void k2_scatter(
    const int* __restrict__ ei1, const int* __restrict__ ei2,
    float* __restrict__ ws_f, const int* __restrict__ ws_i)
{
    int b = blockIdx.x, t = threadIdx.x;

    if (b < K2_G1_BLOCKS) {
        int src, dst;
        if (b < cE1) { src = ei1[b]; dst = ei1[cE1 + b]; }
        else         { src = dst = b - cE1; }                        // self loop
        float norm = rsqrtf((float)(ws_i[OFF_DEG1 + src] + 1))
                   * rsqrtf((float)(ws_i[OFF_DEG1 + dst] + 1));
        if (t < cO1)
            atomicAdd(&ws_f[OFF_G1 + dst * cO1 + t],
                      ws_f[OFF_H1 + src * cO1 + t] * norm);
        return;
    }
    b -= K2_G1_BLOCKS;

    int e = b * 256 + t;
    if (e < cE2 + cN2) {
        int src, dst;
        if (e < cE2) { src = ei2[e]; dst = ei2[cE2 + e]; }
        else         { src = dst = e - cE2; }                        // self loop
        float norm = rsqrtf((float)(ws_i[OFF_DEG2 + src] + 1))
                   * rsqrtf((float)(ws_i[OFF_DEG2 + dst] + 1));
        float2 h = reinterpret_cast<const float2*>(ws_f + OFF_H2)[src];
        atomicAdd(&ws_f[OFF_G2 + dst * 2 + 0], h.x * norm);
        atomicAdd(&ws_f[OFF_G2 + dst * 2 + 1], h.y * norm);
    }
}

// ---------------- K3: bias + reshape/concat + relu + final linear ----------------
__global__ __launch_bounds__(128) void k3_head(
    const float* __restrict__ ws_f,
    const float* __restrict__ b1, const float* __restrict__ b2,
    const float* __restrict__ Wf, const float* __restrict__ bf,
    float* __restrict__ out)
{
    __shared__ float sh[113];
    int r = blockIdx.x, t = threadIdx.x;
    if (t < 113) {
        float v;
        if (t < 68) { int f = r * 68 + t;        v = ws_f[OFF_G1 + f] + b1[f % 200]; }
        else        { int f = r * 45 + (t - 68); v = ws_f[OFF_G2 + f] + b2[f & 1];  }
        sh[t] = fmaxf(v, 0.f);
    }
    __syncthreads();
    if (t < 5) {
        float s = bf[t];
        #pragma unroll 1
        for (int k = 0; k < 113; ++k)
            s = fmaf(sh[k], Wf[k * 5 + t], s);
        out[r * 5 + t] = s;
    }
}

extern "C" void kernel_launch(void* const* d_in, const int* in_sizes, int n_in,
                              void* d_out, int out_size, void* d_ws, size_t ws_size,
                              hipStream_t stream)
{
    const float* x1 = (const float*)d_in[0];
    const float* x2 = (const float*)d_in[1];
    const float* W1 = (const float*)d_in[2];
    const float* b1 = (const float*)d_in[3];
    const float* W2 = (const float*)d_in[4];
    const float* b2 = (const float*)d_in[5];
    const float* Wf = (const float*)d_in[6];
    const float* bf = (const float*)d_in[7];
    const int*   ei1 = (const int*)d_in[8];
    const int*   ei2 = (const int*)d_in[9];
    float* ws_f = (float*)d_ws;
    int*   ws_i = (int*)d_ws;
    float* out  = (float*)d_out;

    hipMemsetAsync(d_ws, 0, ZERO_WORDS * sizeof(float), stream);
    k1_gemm_deg<<<K1_GRID, 256, 0, stream>>>(x1, x2, W1, W2, ei1, ei2, ws_f, ws_i);
    k2_scatter<<<K2_GRID, 256, 0, stream>>>(ei1, ei2, ws_f, ws_i);
    k3_head<<<250, 128, 0, stream>>>(ws_f, b1, b2, Wf, bf, out);
}